// Round 4
// baseline (201.435 us; speedup 1.0000x reference)
//
#include <hip/hip_runtime.h>

#define INF_DELTA 1e10f
#define RM_EPS 1e-10f
#define LOG2E 1.4426950408889634f

__device__ __forceinline__ float softplus_log2(float x) {
    // log2(1+e^x) = relu(x)*log2e + log2(1 + exp2(-|x|*log2e))
    const float q  = __builtin_amdgcn_exp2f(-__builtin_fabsf(x) * LOG2E);
    const float l2 = __builtin_amdgcn_logf(1.0f + q);
    return __builtin_fmaf(__builtin_fmaxf(x, 0.0f), LOG2E, l2);
}

// 16 lanes per ray, 4 samples per lane, 4 rays per wave, 16 rays per block.
__global__ __launch_bounds__(256) void raymarch_kernel(
    const float4* __restrict__ colors4,    // (n_rays, 48) as float4
    const float4* __restrict__ densities4, // (n_rays, 16)
    const float4* __restrict__ depths4,    // (n_rays, 16)
    float* __restrict__ rgb_out,           // (n_rays, 3)
    float* __restrict__ depth_out,         // (n_rays,)
    float4* __restrict__ weights4,         // (n_rays, 16)
    float* __restrict__ trans_out,         // (n_rays,)
    int n_rays)
{
    const int lane = threadIdx.x & 63;
    const int sl   = lane & 15;                       // sub-lane within ray group
    const int ray  = blockIdx.x * 16 + (((int)threadIdx.x >> 6) << 2) + (lane >> 4);
    if (ray >= n_rays) return;

    const long vbase = (long)ray * 16 + sl;

    // Dense float4 loads: lanes of a group cover contiguous memory.
    const float4 d4 = depths4[vbase];
    const float4 x4 = densities4[vbase];
    const float4* cp = colors4 + (long)ray * 48 + sl * 3;
    const float4 ca = cp[0], cb = cp[1], cc = cp[2];

    // Next lane's first depth (for this lane's last delta). sl==15 => s==63 => INF.
    const float dnext = __shfl_down(d4.x, 1, 64);
    const float del0 = d4.y - d4.x;
    const float del1 = d4.z - d4.y;
    const float del2 = d4.w - d4.z;
    const float del3 = (sl == 15) ? INF_DELTA : (dnext - d4.w);

    // y = exp(-delta * softplus(x)) — 4 independent chains (ILP)
    const float y0 = __builtin_amdgcn_exp2f(-del0 * softplus_log2(x4.x));
    const float y1 = __builtin_amdgcn_exp2f(-del1 * softplus_log2(x4.y));
    const float y2 = __builtin_amdgcn_exp2f(-del2 * softplus_log2(x4.z));
    const float y3 = __builtin_amdgcn_exp2f(-del3 * softplus_log2(x4.w));

    const float t0 = y0 + RM_EPS, t1 = y1 + RM_EPS;
    const float t2 = y2 + RM_EPS, t3 = y3 + RM_EPS;

    // In-lane exclusive prefix products
    const float p1 = t0, p2 = t0 * t1, p3 = p2 * t2;
    const float ptot = p3 * t3;

    // Inclusive scan-product of ptot over the 16-lane segment (4 steps)
    float P = ptot;
    #pragma unroll
    for (int off = 1; off < 16; off <<= 1) {
        const float o = __shfl_up(P, off, 16);
        P *= (sl >= off) ? o : 1.0f;
    }
    float Pexcl = __shfl_up(P, 1, 16);
    if (sl == 0) Pexcl = 1.0f;
    const float finalT = __shfl(P, 15, 16);   // segment lane 15 = full product

    // Weights
    const float w0 = (1.0f - y0) * Pexcl;
    const float w1 = (1.0f - y1) * (Pexcl * p1);
    const float w2 = (1.0f - y2) * (Pexcl * p2);
    const float w3 = (1.0f - y3) * (Pexcl * p3);

    float4 wv; wv.x = w0; wv.y = w1; wv.z = w2; wv.w = w3;
    weights4[vbase] = wv;   // dense float4 store

    // Per-lane partial sums. Color channel mapping within the 3 float4s:
    // ca=(j0c0,j0c1,j0c2,j1c0) cb=(j1c1,j1c2,j2c0,j2c1) cc=(j2c2,j3c0,j3c1,j3c2)
    float s0 = w0*ca.x + w1*ca.w + w2*cb.z + w3*cc.y;   // channel 0
    float s1 = w0*ca.y + w1*cb.x + w2*cb.w + w3*cc.z;   // channel 1
    float s2 = w0*ca.z + w1*cb.y + w2*cc.x + w3*cc.w;   // channel 2
    float s3 = w0*d4.x + w1*d4.y + w2*d4.z + w3*d4.w;   // depth

    // Shared-step reduction over 16 lanes: xor1,xor2 on all four values,
    // then each lane keeps channel (sl&3) and finishes with xor4,xor8.
    #pragma unroll
    for (int off = 1; off <= 2; off <<= 1) {
        s0 += __shfl_xor(s0, off, 16);
        s1 += __shfl_xor(s1, off, 16);
        s2 += __shfl_xor(s2, off, 16);
        s3 += __shfl_xor(s3, off, 16);
    }
    const int sel = sl & 3;
    float v = (sel == 0) ? s0 : (sel == 1) ? s1 : (sel == 2) ? s2 : s3;
    #pragma unroll
    for (int off = 4; off < 16; off <<= 1) {
        v += __shfl_xor(v, off, 16);
    }
    // lanes sl=0..3 of each group hold the 4 totals

    if (sl < 3) {
        rgb_out[(long)ray * 3 + sl] = v;
    } else if (sl == 3) {
        depth_out[ray] = v;
    } else if (sl == 4) {
        trans_out[ray] = finalT;
    }
}

extern "C" void kernel_launch(void* const* d_in, const int* in_sizes, int n_in,
                              void* d_out, int out_size, void* d_ws, size_t ws_size,
                              hipStream_t stream) {
    const float4* colors4    = (const float4*)d_in[0];
    const float4* densities4 = (const float4*)d_in[1];
    const float4* depths4    = (const float4*)d_in[2];

    const int n_rays = in_sizes[1] / 64;

    float* out      = (float*)d_out;
    float* rgb      = out;                              // n_rays*3
    float* depth_o  = rgb + (long)n_rays * 3;           // n_rays
    float4* weights = (float4*)(depth_o + n_rays);      // n_rays*16 float4
    float* trans    = (float*)(weights + (long)n_rays * 16);

    const int blocks = (n_rays + 15) / 16;   // 16 rays per 256-thread block
    raymarch_kernel<<<blocks, 256, 0, stream>>>(
        colors4, densities4, depths4, rgb, depth_o, weights, trans, n_rays);
}